// Round 14
// baseline (88.155 us; speedup 1.0000x reference)
//
#include <hip/hip_runtime.h>
#include <cstdint>
#include <cfloat>
#include <cmath>

#define NPTS 65536
#define NB 16
#define NS 20
#define KK 10
#define FPB 16      // FPS blocks per batch
#define NSm1 (NS - 1)
#define NCH 8       // knn chunks per batch (8192 pts each)
#define NSG 4       // seed groups (5 seeds each)
#define SPG 5       // seeds per group

struct InitIdx { int idx[NB]; };

static __device__ __forceinline__ unsigned long long
agent_ld(const unsigned long long* p) {
    return __hip_atomic_load(p, __ATOMIC_RELAXED, __HIP_MEMORY_SCOPE_AGENT);
}

// ---------------- Kernel 1: distributed FPS (R12-verbatim, 46.5 us) ---------
__global__ __launch_bounds__(1024) void fps_kernel(const float* __restrict__ pcs,
                                                   int* __restrict__ seeds,
                                                   unsigned long long* __restrict__ fkey,
                                                   InitIdx init) {
    const int u   = blockIdx.x;
    const int xcd = u & 7;              // XCD heuristic (perf-only)
    const int k   = u >> 3;             // 0..31
    const int b   = 2 * xcd + (k >> 4); // batch
    const int j   = k & 15;             // block-in-batch
    const int t   = threadIdx.x;
    const int lane = t & 63;
    const int w    = t >> 6;
    const float* __restrict__ base = pcs + (size_t)b * NPTS * 3;
    const int pbase = j * 4096 + t * 4; // 4 contiguous points per thread

    const float4* q4 = reinterpret_cast<const float4*>(base + (size_t)pbase * 3);
    float4 A = q4[0], Bv = q4[1], Cv = q4[2];
    float x[4] = { A.x, A.w, Bv.z, Cv.y };
    float y[4] = { A.y, Bv.x, Bv.w, Cv.z };
    float z[4] = { A.z, Bv.y, Cv.x, Cv.w };
    float dm[4] = { 1e10f, 1e10f, 1e10f, 1e10f };

    __shared__ float s_val[16];
    __shared__ int   s_idx[16];
    __shared__ int   s_far;

    int far = init.idx[b];

    for (int s = 0; s < NS; ++s) {
        if (j == 0 && t == 0) seeds[b * NS + s] = far;   // seed s BEFORE update
        if (s == NSm1) break;                            // last update unused

        const float* c = base + (size_t)far * 3;         // uniform, cached
        const float cx = c[0], cy = c[1], cz = c[2];

        float bestv = -1.0f;
        int   besti = 0;
#pragma unroll
        for (int q = 0; q < 4; ++q) {
            // match XLA: rounded sub/mul, sequential adds, NO fma contraction
            float dx = __fsub_rn(x[q], cx);
            float dy = __fsub_rn(y[q], cy);
            float dz = __fsub_rn(z[q], cz);
            float d  = __fadd_rn(__fadd_rn(__fmul_rn(dx, dx), __fmul_rn(dy, dy)),
                                 __fmul_rn(dz, dz));
            dm[q] = fminf(dm[q], d);
            // q ascending = index ascending; strict > keeps first occurrence
            if (dm[q] > bestv) { bestv = dm[q]; besti = pbase + q; }
        }
#pragma unroll
        for (int off = 32; off >= 1; off >>= 1) {
            float ov = __shfl_down(bestv, off);
            int   oi = __shfl_down(besti, off);
            if (ov > bestv || (ov == bestv && oi < besti)) { bestv = ov; besti = oi; }
        }
        if (lane == 0) { s_val[w] = bestv; s_idx[w] = besti; }
        __syncthreads();                                 // B1

        if (w == 0) {
            // parallel 16-lane block reduce -> packed key -> publish
            unsigned long long kv = 0ULL;
            if (lane < 16) {
                kv = ((unsigned long long)__float_as_uint(s_val[lane]) << 32) |
                     (unsigned long long)(0xFFFFFFFFu - (unsigned int)s_idx[lane]);
            }
#pragma unroll
            for (int off = 8; off >= 1; off >>= 1) {
                unsigned int lo = (unsigned int)kv, hi = (unsigned int)(kv >> 32);
                unsigned int olo = (unsigned int)__shfl_xor((int)lo, off);
                unsigned int ohi = (unsigned int)__shfl_xor((int)hi, off);
                unsigned long long o = ((unsigned long long)ohi << 32) | olo;
                if (o > kv) kv = o;
            }
            unsigned long long* fp = fkey + (size_t)(b * NS + s) * FPB;
            if (lane == 0)
                __hip_atomic_store(&fp[j], kv, __ATOMIC_RELAXED,
                                   __HIP_MEMORY_SCOPE_AGENT);

            // 3-deep pipelined poll of the 16 slots (lane l watches slot l&15)
            const unsigned long long* sl = fp + (lane & 15);
            unsigned long long p0 = agent_ld(sl);
            unsigned long long p1 = agent_ld(sl);
            unsigned long long p2 = agent_ld(sl);
            unsigned long long v;
            for (;;) {
                if (!__any(p0 == 0ULL)) { v = p0; break; }
                p0 = agent_ld(sl);
                if (!__any(p1 == 0ULL)) { v = p1; break; }
                p1 = agent_ld(sl);
                if (!__any(p2 == 0ULL)) { v = p2; break; }
                p2 = agent_ld(sl);
            }
#pragma unroll
            for (int off = 32; off >= 1; off >>= 1) {
                unsigned int lo = (unsigned int)v, hi = (unsigned int)(v >> 32);
                unsigned int olo = (unsigned int)__shfl_xor((int)lo, off);
                unsigned int ohi = (unsigned int)__shfl_xor((int)hi, off);
                unsigned long long o = ((unsigned long long)ohi << 32) | olo;
                if (o > v) v = o;
            }
            if (lane == 0)
                s_far = (int)(0xFFFFFFFFu - (unsigned int)(v & 0xFFFFFFFFull));
        }
        __syncthreads();                                 // B2
        far = s_far;
    }
}

// ---------------- Kernel 2: multi-seed knn scan (read-once per seed-group) --
// Block = 256 thr handles (batch, chunk of 8192 pts, group of 5 seeds).
// Each point is loaded ONCE and tested against 5 seeds -> total point reads
// drop 20x -> 4x vs per-seed scanning (R13's knn was re-read-volume-bound).
// Per-thread state: 5 lists x 11, statically indexed (med3 branchless insert,
// no serial chain). Grid 16x8x4 = 512 = exactly 2 blocks/CU.
// Each wave 11-pops each list into part[pair][chunk][wave][11].
__global__ __launch_bounds__(256) void knn_scan(const float* __restrict__ pcs,
                                                const int* __restrict__ seeds,
                                                float* __restrict__ part) {
    const int u   = blockIdx.x;        // 0..511
    const int xcd = u & 7;
    const int k   = u >> 3;            // 0..63
    const int b   = 2 * xcd + (k >> 5);
    const int rem = k & 31;
    const int ch  = rem >> 2;          // chunk 0..7
    const int sg  = rem & 3;           // seed group 0..3
    const int t = threadIdx.x;         // 0..255
    const int lane = t & 63;
    const int w = t >> 6;              // wave 0..3
    const float* __restrict__ base = pcs + (size_t)b * NPTS * 3;

    // the group's 5 seed coords (uniform broadcast loads, cached)
    float scx[SPG], scy[SPG], scz[SPG];
#pragma unroll
    for (int g = 0; g < SPG; ++g) {
        const int sidx = seeds[b * NS + sg * SPG + g];
        scx[g] = base[(size_t)sidx * 3 + 0];
        scy[g] = base[(size_t)sidx * 3 + 1];
        scz[g] = base[(size_t)sidx * 3 + 2];
    }

    float lst[SPG][11];
#pragma unroll
    for (int g = 0; g < SPG; ++g)
#pragma unroll
        for (int jj = 0; jj < 11; ++jj) lst[g][jj] = FLT_MAX;

    // 8192 pts / 256 thr = 32 pts/thread = 8 iterations of 4 contiguous pts
    for (int i = 0; i < 8; ++i) {
        const int pbase = ch * 8192 + i * 1024 + t * 4;
        const float4* q4 = reinterpret_cast<const float4*>(base + (size_t)pbase * 3);
        float4 A = q4[0], Bv = q4[1], Cv = q4[2];
        float px[4] = { A.x, A.w, Bv.z, Cv.y };
        float py[4] = { A.y, Bv.x, Bv.w, Cv.z };
        float pz[4] = { A.z, Bv.y, Cv.x, Cv.w };
#pragma unroll
        for (int q = 0; q < 4; ++q) {
#pragma unroll
            for (int g = 0; g < SPG; ++g) {
                float dx = __fsub_rn(px[q], scx[g]);
                float dy = __fsub_rn(py[q], scy[g]);
                float dz = __fsub_rn(pz[q], scz[g]);
                float sq = __fadd_rn(__fadd_rn(__fmul_rn(dx, dx),
                                               __fmul_rn(dy, dy)),
                                     __fmul_rn(dz, dz));
                // branchless sorted insert (independent med3 ops)
#pragma unroll
                for (int jj = 10; jj >= 1; --jj)
                    lst[g][jj] = __builtin_amdgcn_fmed3f(lst[g][jj - 1],
                                                         lst[g][jj], sq);
                lst[g][0] = fminf(lst[g][0], sq);
            }
        }
    }

    // wave-level top-11 per list: 11 rounds of (wave-min of heads, pop one)
#pragma unroll
    for (int g = 0; g < SPG; ++g) {
        const int s = sg * SPG + g;
        float* pr = part + ((size_t)(b * NS + s) * NCH * 4 + ch * 4 + w) * 11;
        for (int r = 0; r < 11; ++r) {
            float v = lst[g][0];
#pragma unroll
            for (int off = 32; off >= 1; off >>= 1) v = fminf(v, __shfl_xor(v, off));
            unsigned long long m = __ballot(lst[g][0] == v);
            if (lane == (int)__ffsll(m) - 1) {   // pop exactly one copy
#pragma unroll
                for (int jj = 0; jj < 10; ++jj) lst[g][jj] = lst[g][jj + 1];
                lst[g][10] = FLT_MAX;
            }
            if (lane == 0) pr[r] = v;
        }
    }
}

// ---------------- Kernel 3: merge 352 -> top-11 + repulsion epilogue --------
// 320 blocks x 1 wave; lanes hold 6 candidates (352 = 5*64 + 32), 11 rounds
// of (min over regs, wave butterfly, pop-one-copy), epilogue on lane 0.
__global__ __launch_bounds__(64) void knn_merge(const float* __restrict__ part,
                                               float* __restrict__ out) {
    const int pair = blockIdx.x;       // 0..319
    const int lane = threadIdx.x;      // 0..63
    const float* flat = part + (size_t)pair * 352;
    float a0 = flat[lane];
    float a1 = flat[lane + 64];
    float a2 = flat[lane + 128];
    float a3 = flat[lane + 192];
    float a4 = flat[lane + 256];
    float a5 = (lane < 32) ? flat[lane + 320] : FLT_MAX;

    const float HH = (float)(0.01 * 0.01);   // JAX weak-typed scalar H*H
    float acc = 0.0f;
#pragma unroll
    for (int r = 0; r < 11; ++r) {
        float mymin = fminf(fminf(fminf(a0, a1), fminf(a2, a3)), fminf(a4, a5));
        float v = mymin;
#pragma unroll
        for (int off = 32; off >= 1; off >>= 1) v = fminf(v, __shfl_xor(v, off));
        unsigned long long m = __ballot(mymin == v);
        if (lane == (int)__ffsll(m) - 1) {   // pop exactly one copy
            if (a0 == v)      a0 = FLT_MAX;
            else if (a1 == v) a1 = FLT_MAX;
            else if (a2 == v) a2 = FLT_MAX;
            else if (a3 == v) a3 = FLT_MAX;
            else if (a4 == v) a4 = FLT_MAX;
            else              a5 = FLT_MAX;
        }
        if (lane == 0 && r >= 1) {           // r==0 is self (dist 0)
            float sq = v;
            float d  = (sq == 0.0f) ? 0.0f : __fsqrt_rn(sq);
            float q2 = __fmul_rn(d, d);
            float wt = expf(__fdiv_rn(-q2, HH));
            acc = __fadd_rn(acc, -__fmul_rn(d, wt));
        }
    }
    if (lane == 0) atomicAdd(out, acc * 0.0625f);   // mean over B=16
}

// ---------------- Host: JAX threefry2x32 (partitionable mode) ---------------
static inline uint32_t rotl32(uint32_t x, uint32_t d) { return (x << d) | (x >> (32 - d)); }

static void tf2x32(uint32_t k0, uint32_t k1, uint32_t x0, uint32_t x1,
                   uint32_t& y0, uint32_t& y1) {
    const uint32_t ks[3] = { k0, k1, k0 ^ k1 ^ 0x1BD11BDAu };
    const uint32_t rotA[4] = { 13, 15, 26, 6 };
    const uint32_t rotB[4] = { 17, 29, 16, 24 };
    uint32_t v0 = x0 + ks[0], v1 = x1 + ks[1];
    for (int i = 0; i < 5; ++i) {
        const uint32_t* rot = (i % 2 == 0) ? rotA : rotB;
        for (int j = 0; j < 4; ++j) {
            v0 += v1;
            v1 = rotl32(v1, rot[j]);
            v1 ^= v0;
        }
        v0 += ks[(i + 1) % 3];
        v1 += ks[(i + 2) % 3] + (uint32_t)(i + 1);
    }
    y0 = v0; y1 = v1;
}

extern "C" void kernel_launch(void* const* d_in, const int* in_sizes, int n_in,
                              void* d_out, int out_size, void* d_ws, size_t ws_size,
                              hipStream_t stream) {
    const float* pcs = (const float*)d_in[0];
    float* out = (float*)d_out;

    // ws: [0,1280) seeds (int); [2048,43008) fps keys u64[16*20*16];
    //     [49152, 49152+320*352*4=499712) part f32
    int* seeds               = (int*)d_ws;
    unsigned long long* fkey = (unsigned long long*)((char*)d_ws + 2048);
    float* part              = (float*)((char*)d_ws + 49152);

    // jax.random.key(1) -> threefry key (0,1), partitionable mode:
    //   split foldlike: k2 = threefry((0,1),(0,1)) both words
    //   random_bits: counters (0,i), out = y0 ^ y1; randint span 2^16 -> mask
    uint32_t k2_0, k2_1;
    tf2x32(0u, 1u, 0u, 1u, k2_0, k2_1);
    InitIdx init;
    for (int i = 0; i < NB; ++i) {
        uint32_t y0, y1;
        tf2x32(k2_0, k2_1, 0u, (uint32_t)i, y0, y1);
        init.idx[i] = (int)((y0 ^ y1) & 0xFFFFu);
    }

    hipMemsetAsync(d_ws, 0, 43008, stream);   // seeds + fps keys
    hipMemsetAsync(d_out, 0, sizeof(float), stream);

    hipLaunchKernelGGL(fps_kernel, dim3(NB * FPB), dim3(1024), 0, stream,
                       pcs, seeds, fkey, init);
    hipLaunchKernelGGL(knn_scan, dim3(512), dim3(256), 0, stream,
                       pcs, seeds, part);
    hipLaunchKernelGGL(knn_merge, dim3(320), dim3(64), 0, stream,
                       part, out);
}